// Round 8
// baseline (40.359 us; speedup 1.0000x reference)
//
#include <hip/hip_runtime.h>
#include <hip/hip_bf16.h>
#include <math.h>

#define NN 512
#define DD 128
#define ROWS 1024
#define NR 4

typedef float f32x2 __attribute__((ext_vector_type(2)));

__device__ __forceinline__ float sigmoidf_(float z){ return 1.0f/(1.0f + __expf(-z)); }

// unpack 4 consecutive bf16 (as uint2) -> float4, exact
__device__ __forceinline__ float4 bf4(uint2 u) {
    float4 w;
    w.x = __uint_as_float(u.x << 16);
    w.y = __uint_as_float(u.x & 0xffff0000u);
    w.z = __uint_as_float(u.y << 16);
    w.w = __uint_as_float(u.y & 0xffff0000u);
    return w;
}

// ---------------------------------------------------------------------------
// Kernel 1 (512 threads, 256 blocks): per-row transforms, 4-way split-d GEMVs.
//   h    = x @ W_lin^T + b_lin          (split-d partials, LDS combine)
//   hm1  = h @ W_m1[:, :128]^T + b_m1   (stored BF16)
//   dotL = h . W_att[0:128], dotR = h . W_att[128:256]   (one wave each)
//   blocks 0..47: transpose an 8-row slice of W_m2/W_o1/W_o2 into BF16 Wt[d][o].
// ---------------------------------------------------------------------------
__global__ __launch_bounds__(512) void k_rows(
    const float* __restrict__ x, const float* __restrict__ W_lin, const float* __restrict__ b_lin,
    const float* __restrict__ W_m1, const float* __restrict__ b_m1,
    const float* __restrict__ W_att,
    const float* __restrict__ W_m2, const float* __restrict__ W_o1, const float* __restrict__ W_o2,
    float* __restrict__ h, __hip_bfloat16* __restrict__ hm1b,
    float* __restrict__ dotL, float* __restrict__ dotR,
    __hip_bfloat16* __restrict__ Wt_m2, __hip_bfloat16* __restrict__ Wt_o1,
    __hip_bfloat16* __restrict__ Wt_o2)
{
    const int r0   = blockIdx.x * NR;
    const int t    = threadIdx.x;        // 0..511
    const int rr   = t >> 7;             // row-in-block (combine phases)
    const int o    = t & 127;            // output dim
    const int q    = t >> 7;             // d-quarter for split-d GEMVs
    const int g    = t >> 6;             // wave 0..7
    const int lane = t & 63;

    __shared__ float xs[NR][DD];         // x staging
    __shared__ float hs[NR][DD];         // h
    __shared__ float pb2[4][NR][DD];     // split-d partials

    // stage x: 512 floats = the block's 4 rows
    ((float*)xs)[t] = x[r0 * DD + t];
    __syncthreads();

    // GEMV1: h = x @ W_lin^T + b_lin  (thread (q,o) covers d in [32q, 32q+32))
    {
        float a[NR] = {0.f, 0.f, 0.f, 0.f};
        const float4* wp = (const float4*)(W_lin + o * DD + q * 32);
        #pragma unroll
        for (int k = 0; k < 8; k++) {
            float4 w4 = wp[k];
            int d = q * 32 + 4 * k;
            #pragma unroll
            for (int r = 0; r < NR; r++) {
                float4 xv = *(const float4*)&xs[r][d];
                a[r] = fmaf(xv.x, w4.x, a[r]);
                a[r] = fmaf(xv.y, w4.y, a[r]);
                a[r] = fmaf(xv.z, w4.z, a[r]);
                a[r] = fmaf(xv.w, w4.w, a[r]);
            }
        }
        #pragma unroll
        for (int r = 0; r < NR; r++) pb2[q][r][o] = a[r];
    }
    __syncthreads();
    {
        float hreg = b_lin[o] + pb2[0][rr][o] + pb2[1][rr][o]
                              + pb2[2][rr][o] + pb2[3][rr][o];
        hs[rr][o] = hreg;
        h[(r0 + rr) * DD + o] = hreg;
    }
    __syncthreads();

    // dots: wave g handles row = g&3, side = g>>2 (0 = L, 1 = R)
    {
        int row = g & 3;
        const float* wa = W_att + (g >> 2) * DD;
        float p = hs[row][lane] * wa[lane] + hs[row][lane + 64] * wa[lane + 64];
        #pragma unroll
        for (int off = 32; off >= 1; off >>= 1) p += __shfl_down(p, off, 64);
        if (lane == 0) {
            if (g < 4) dotL[r0 + row] = p;
            else       dotR[r0 + row] = p;
        }
    }

    // GEMV2: hm1 = h @ W_m1[:, :128]^T + b_m1  (row stride 129), store BF16
    {
        float a[NR] = {0.f, 0.f, 0.f, 0.f};
        const float* w2 = W_m1 + o * (DD + 1) + q * 32;
        #pragma unroll
        for (int k = 0; k < 8; k++) {
            int d = q * 32 + 4 * k;
            float w0 = w2[4*k], w1 = w2[4*k+1], w2v = w2[4*k+2], w3 = w2[4*k+3];
            #pragma unroll
            for (int r = 0; r < NR; r++) {
                float4 xv = *(const float4*)&hs[r][d];
                a[r] = fmaf(xv.x, w0,  a[r]);
                a[r] = fmaf(xv.y, w1,  a[r]);
                a[r] = fmaf(xv.z, w2v, a[r]);
                a[r] = fmaf(xv.w, w3,  a[r]);
            }
        }
        #pragma unroll
        for (int r = 0; r < NR; r++) pb2[q][r][o] = a[r];
    }
    __syncthreads();
    {
        float v = b_m1[o] + pb2[0][rr][o] + pb2[1][rr][o]
                          + pb2[2][rr][o] + pb2[3][rr][o];
        hm1b[(r0 + rr) * DD + o] = __float2bfloat16(v);
    }

    // transpose duty: blocks 0..47, one 8-row slice each (global-only, no sync)
    if (blockIdx.x < 48 && t < 128) {
        const int w = blockIdx.x >> 4;
        const int s = blockIdx.x & 15;
        const float* src = (w == 0) ? W_m2 : (w == 1) ? W_o1 : W_o2;
        __hip_bfloat16* dst = (w == 0) ? Wt_m2 : (w == 1) ? Wt_o1 : Wt_o2;
        #pragma unroll
        for (int j = 0; j < 8; j++)
            dst[t * DD + s * 8 + j] = __float2bfloat16(src[(s * 8 + j) * DD + t]);
    }
}

// ---------------------------------------------------------------------------
// Kernel 2: fused attention + message aggregation + output network + LN.
//  - GEMV weights bf16, register-prefetched at kernel top (latency hides
//    under phases A/B instead of serializing phase C).
//  - Phase B packed via __builtin_elementwise_fma/max on ext_vector float2
//    (stays in IR -> schedulable, unlike R6's inline asm).
// ---------------------------------------------------------------------------
__global__ __launch_bounds__(512) void k_msgout(
    const float* __restrict__ adj, const unsigned int* __restrict__ hm1u,
    const float* __restrict__ dotL, const float* __restrict__ dotR,
    const float* __restrict__ W_m1, const float* __restrict__ W_att, const float* __restrict__ b_att,
    const __hip_bfloat16* __restrict__ Wt_m2, const float* __restrict__ b_m2,
    const __hip_bfloat16* __restrict__ Wt_o1, const float* __restrict__ b_o1,
    const __hip_bfloat16* __restrict__ Wt_o2, const float* __restrict__ b_o2,
    const float* __restrict__ h, const float* __restrict__ ln_g, const float* __restrict__ ln_b,
    float* __restrict__ out, float* __restrict__ out_adj)
{
    const int r0   = blockIdx.x * NR;
    const int b    = r0 >> 9;
    const int t    = threadIdx.x;        // 0..511
    const int g    = t >> 6;             // wave 0..7
    const int lane = t & 63;
    const int rr   = t >> 7;             // row-in-block (combine/LN phases)
    const int o    = t & 127;            // output dim   (combine/LN phases)
    const int oq   = t & 31;             // GEMV: output quad (o = 4*oq..+3)
    const int dg   = t >> 5;             // GEMV: d-group (d = dg*8..+7)

    __shared__ float2 aa[NR][NN];        // (adj, att) 16KB
    __shared__ float2 red[8][NR][64];    // sweep partials 16KB
    __shared__ float  pb[4][4][16][32];  // GEMV partials [j][r][dg][oq] 32KB
    __shared__ float  vs[NR][DD];        // GEMV ping
    __shared__ float  vs2[NR][DD];       // GEMV pong
    __shared__ float2 wa1s[64];
    __shared__ float  satt[NR];
    __shared__ float  redsc[2][2][NR];

    // ---- register-prefetch all GEMV weights (bf16, consumed in phase C) ----
    uint2 pre1[8], pre2[8], pre3[8];
    {
        const unsigned short* w1 = (const unsigned short*)Wt_m2;
        const unsigned short* w2 = (const unsigned short*)Wt_o1;
        const unsigned short* w3 = (const unsigned short*)Wt_o2;
        #pragma unroll
        for (int k = 0; k < 8; k++) {
            int off = (dg * 8 + k) * DD + oq * 4;
            pre1[k] = *(const uint2*)(w1 + off);
            pre2[k] = *(const uint2*)(w2 + off);
            pre3[k] = *(const uint2*)(w3 + off);
        }
    }

    if (t < 64)
        wa1s[t] = make_float2(W_m1[(2 * t) * (DD + 1) + DD],
                              W_m1[(2 * t + 1) * (DD + 1) + DD]);
    const float wAdj = W_att[2 * DD];
    const float bA   = b_att[0];

    // ---- Phase A: attention + adj passthrough ----
    {
        float drm = dotR[b * NN + t];
        #pragma unroll
        for (int i = 0; i < NR; i++) {
            float a = adj[(r0 + i) * NN + t];
            out_adj[(r0 + i) * NN + t] = a;
            float z = dotL[r0 + i] + drm + a * wAdj + bA;
            aa[i][t] = make_float2(a, sigmoidf_(z));
        }
    }
    __syncthreads();

    if (g < NR) {   // s_att
        float s = 0.f;
        #pragma unroll
        for (int k = 0; k < 8; k++) s += aa[g][lane + 64 * k].y;
        #pragma unroll
        for (int off = 32; off >= 1; off >>= 1) s += __shfl_down(s, off, 64);
        if (lane == 0) satt[g] = s;
    }

    // ---- Phase B: neighbor sweep (packed f32x2 via elementwise builtins) ----
    {
        f32x2 agg[NR];
        #pragma unroll
        for (int r = 0; r < NR; r++) agg[r] = (f32x2){0.f, 0.f};
        float2 wa0 = wa1s[lane];
        f32x2 wav = {wa0.x, wa0.y};
        const f32x2 zero2 = {0.f, 0.f};
        const unsigned int* hbase = hm1u + (size_t)b * NN * 64 + lane;
        #pragma unroll 4
        for (int m = g; m < NN; m += 8) {
            unsigned int u = hbase[m * 64];
            f32x2 hv;
            hv.x = __uint_as_float(u << 16);           // low bf16 -> f32 (exact)
            hv.y = __uint_as_float(u & 0xffff0000u);   // high bf16 -> f32
            #pragma unroll
            for (int r = 0; r < NR; r++) {
                float2 at = aa[r][m];                  // LDS broadcast
                f32x2 adj2 = {at.x, at.x};
                f32x2 att2 = {at.y, at.y};
                f32x2 uu = __builtin_elementwise_fma(adj2, wav, hv);
                uu = __builtin_elementwise_max(uu, zero2);
                agg[r] = __builtin_elementwise_fma(att2, uu, agg[r]);
            }
        }
        #pragma unroll
        for (int r = 0; r < NR; r++) red[g][r][lane] = make_float2(agg[r].x, agg[r].y);
    }
    __syncthreads();
    {   // combine sweep partials -> vs = aggm
        float s = 0.f;
        #pragma unroll
        for (int gg = 0; gg < 8; gg++)
            s += ((const float*)&red[gg][rr][0])[o];
        vs[rr][o] = s;
    }
    __syncthreads();

    // ---- Phase C: three GEMVs with transposed bf16 weights (prefetched) ----
    // GEMV1: v1 = aggm @ W_m2^T + b_m2 * s_att
    {
        float a0[4], a1[4], a2[4], a3[4];
        #pragma unroll
        for (int r = 0; r < 4; r++) { a0[r]=0.f; a1[r]=0.f; a2[r]=0.f; a3[r]=0.f; }
        #pragma unroll
        for (int k = 0; k < 8; k++) {
            int d = dg * 8 + k;
            float4 w4 = bf4(pre1[k]);
            #pragma unroll
            for (int r = 0; r < 4; r++) {
                float xv = vs[r][d];
                a0[r] = fmaf(w4.x, xv, a0[r]);
                a1[r] = fmaf(w4.y, xv, a1[r]);
                a2[r] = fmaf(w4.z, xv, a2[r]);
                a3[r] = fmaf(w4.w, xv, a3[r]);
            }
        }
        #pragma unroll
        for (int r = 0; r < 4; r++) {
            pb[0][r][dg][oq] = a0[r]; pb[1][r][dg][oq] = a1[r];
            pb[2][r][dg][oq] = a2[r]; pb[3][r][dg][oq] = a3[r];
        }
    }
    __syncthreads();
    {
        float s = 0.f;
        #pragma unroll
        for (int d16 = 0; d16 < 16; d16++) s += pb[o & 3][rr][d16][o >> 2];
        vs2[rr][o] = s + b_m2[o] * satt[rr];
    }
    __syncthreads();

    // GEMV2: v2 = relu(v1 @ W_o1^T + b_o1)
    {
        float a0[4], a1[4], a2[4], a3[4];
        #pragma unroll
        for (int r = 0; r < 4; r++) { a0[r]=0.f; a1[r]=0.f; a2[r]=0.f; a3[r]=0.f; }
        #pragma unroll
        for (int k = 0; k < 8; k++) {
            int d = dg * 8 + k;
            float4 w4 = bf4(pre2[k]);
            #pragma unroll
            for (int r = 0; r < 4; r++) {
                float xv = vs2[r][d];
                a0[r] = fmaf(w4.x, xv, a0[r]);
                a1[r] = fmaf(w4.y, xv, a1[r]);
                a2[r] = fmaf(w4.z, xv, a2[r]);
                a3[r] = fmaf(w4.w, xv, a3[r]);
            }
        }
        #pragma unroll
        for (int r = 0; r < 4; r++) {
            pb[0][r][dg][oq] = a0[r]; pb[1][r][dg][oq] = a1[r];
            pb[2][r][dg][oq] = a2[r]; pb[3][r][dg][oq] = a3[r];
        }
    }
    __syncthreads();
    {
        float s = 0.f;
        #pragma unroll
        for (int d16 = 0; d16 < 16; d16++) s += pb[o & 3][rr][d16][o >> 2];
        vs[rr][o] = fmaxf(s + b_o1[o], 0.f);
    }
    __syncthreads();

    // GEMV3: v3 = v2 @ W_o2^T + b_o2
    {
        float a0[4], a1[4], a2[4], a3[4];
        #pragma unroll
        for (int r = 0; r < 4; r++) { a0[r]=0.f; a1[r]=0.f; a2[r]=0.f; a3[r]=0.f; }
        #pragma unroll
        for (int k = 0; k < 8; k++) {
            int d = dg * 8 + k;
            float4 w4 = bf4(pre3[k]);
            #pragma unroll
            for (int r = 0; r < 4; r++) {
                float xv = vs[r][d];
                a0[r] = fmaf(w4.x, xv, a0[r]);
                a1[r] = fmaf(w4.y, xv, a1[r]);
                a2[r] = fmaf(w4.z, xv, a2[r]);
                a3[r] = fmaf(w4.w, xv, a3[r]);
            }
        }
        #pragma unroll
        for (int r = 0; r < 4; r++) {
            pb[0][r][dg][oq] = a0[r]; pb[1][r][dg][oq] = a1[r];
            pb[2][r][dg][oq] = a2[r]; pb[3][r][dg][oq] = a3[r];
        }
    }
    __syncthreads();

    float v;
    {
        float s = 0.f;
        #pragma unroll
        for (int d16 = 0; d16 < 16; d16++) s += pb[o & 3][rr][d16][o >> 2];
        v = s + b_o2[o] + h[(r0 + rr) * DD + o];   // + residual
    }

    // layernorm over d (128 threads = 2 waves per row)
    {
        float p1 = v, p2 = v * v;
        #pragma unroll
        for (int off = 32; off >= 1; off >>= 1) {
            p1 += __shfl_down(p1, off, 64);
            p2 += __shfl_down(p2, off, 64);
        }
        int wid = (t >> 6) & 1;
        if ((t & 63) == 0) { redsc[wid][0][rr] = p1; redsc[wid][1][rr] = p2; }
    }
    __syncthreads();
    {
        float sum = redsc[0][0][rr] + redsc[1][0][rr];
        float sq  = redsc[0][1][rr] + redsc[1][1][rr];
        float mu  = sum * (1.0f / DD);
        float var = sq * (1.0f / DD) - mu * mu;
        float inv = rsqrtf(var + 1e-5f);
        out[(r0 + rr) * DD + o] = fmaxf(fmaf((v - mu) * inv, ln_g[o], ln_b[o]), 0.f);
    }
}

extern "C" void kernel_launch(void* const* d_in, const int* in_sizes, int n_in,
                              void* d_out, int out_size, void* d_ws, size_t ws_size,
                              hipStream_t stream)
{
    (void)in_sizes; (void)n_in; (void)out_size; (void)ws_size;
    const float* x     = (const float*)d_in[0];
    const float* adj   = (const float*)d_in[1];
    const float* W_lin = (const float*)d_in[2];
    const float* b_lin = (const float*)d_in[3];
    const float* W_m1  = (const float*)d_in[4];
    const float* b_m1  = (const float*)d_in[5];
    const float* W_m2  = (const float*)d_in[6];
    const float* b_m2  = (const float*)d_in[7];
    const float* W_att = (const float*)d_in[8];
    const float* b_att = (const float*)d_in[9];
    const float* W_o1  = (const float*)d_in[10];
    const float* b_o1  = (const float*)d_in[11];
    const float* W_o2  = (const float*)d_in[12];
    const float* b_o2  = (const float*)d_in[13];
    const float* ln_g  = (const float*)d_in[14];
    const float* ln_b  = (const float*)d_in[15];

    float* out     = (float*)d_out;
    float* out_adj = out + ROWS * DD;

    float* ws    = (float*)d_ws;
    float* hm1   = ws;                    // bf16, 131072 floats reserved
    float* dotL  = ws + 131072;           // 1024
    float* dotR  = ws + 132096;           // 1024
    float* h     = ws + 133120;           // 131072
    float* Wt_m2 = ws + 264192;           // bf16, 16384 floats reserved
    float* Wt_o1 = ws + 280576;           // bf16
    float* Wt_o2 = ws + 296960;           // bf16

    hipLaunchKernelGGL(k_rows, dim3(ROWS / NR), dim3(512), 0, stream,
                       x, W_lin, b_lin, W_m1, b_m1, W_att, W_m2, W_o1, W_o2,
                       h, (__hip_bfloat16*)hm1, dotL, dotR,
                       (__hip_bfloat16*)Wt_m2, (__hip_bfloat16*)Wt_o1, (__hip_bfloat16*)Wt_o2);
    hipLaunchKernelGGL(k_msgout, dim3(ROWS / NR), dim3(512), 0, stream,
                       adj, (const unsigned int*)hm1, dotL, dotR, W_m1, W_att, b_att,
                       (const __hip_bfloat16*)Wt_m2, b_m2,
                       (const __hip_bfloat16*)Wt_o1, b_o1,
                       (const __hip_bfloat16*)Wt_o2, b_o2,
                       h, ln_g, ln_b, out, out_adj);
}

// Round 9
// 26.040 us; speedup vs baseline: 1.5499x; 1.5499x over previous
//
#include <hip/hip_runtime.h>
#include <hip/hip_bf16.h>
#include <math.h>

#define NN 512
#define DD 128
#define ROWS 1024
#define NR 4

__device__ __forceinline__ float sigmoidf_(float z){ return 1.0f/(1.0f + __expf(-z)); }

// unpack 4 consecutive bf16 (as uint2) -> float4, exact
__device__ __forceinline__ float4 bf4(uint2 u) {
    float4 w;
    w.x = __uint_as_float(u.x << 16);
    w.y = __uint_as_float(u.x & 0xffff0000u);
    w.z = __uint_as_float(u.y << 16);
    w.w = __uint_as_float(u.y & 0xffff0000u);
    return w;
}

// ---------------------------------------------------------------------------
// Kernel 1 (512 threads, 256 blocks): per-row transforms, 4-way split-d GEMVs.
//   h    = x @ W_lin^T + b_lin          (split-d partials, LDS combine)
//   hm1  = h @ W_m1[:, :128]^T + b_m1   (stored BF16)
//   dotL = h . W_att[0:128], dotR = h . W_att[128:256]   (one wave each)
//   blocks 0..47: transpose an 8-row slice of W_m2/W_o1/W_o2 into BF16 Wt[d][o].
// ---------------------------------------------------------------------------
__global__ __launch_bounds__(512) void k_rows(
    const float* __restrict__ x, const float* __restrict__ W_lin, const float* __restrict__ b_lin,
    const float* __restrict__ W_m1, const float* __restrict__ b_m1,
    const float* __restrict__ W_att,
    const float* __restrict__ W_m2, const float* __restrict__ W_o1, const float* __restrict__ W_o2,
    float* __restrict__ h, __hip_bfloat16* __restrict__ hm1b,
    float* __restrict__ dotL, float* __restrict__ dotR,
    __hip_bfloat16* __restrict__ Wt_m2, __hip_bfloat16* __restrict__ Wt_o1,
    __hip_bfloat16* __restrict__ Wt_o2)
{
    const int r0   = blockIdx.x * NR;
    const int t    = threadIdx.x;        // 0..511
    const int rr   = t >> 7;             // row-in-block (combine phases)
    const int o    = t & 127;            // output dim
    const int q    = t >> 7;             // d-quarter for split-d GEMVs
    const int g    = t >> 6;             // wave 0..7
    const int lane = t & 63;

    __shared__ float xs[NR][DD];         // x staging
    __shared__ float hs[NR][DD];         // h
    __shared__ float pb2[4][NR][DD];     // split-d partials

    // stage x: 512 floats = the block's 4 rows
    ((float*)xs)[t] = x[r0 * DD + t];
    __syncthreads();

    // GEMV1: h = x @ W_lin^T + b_lin  (thread (q,o) covers d in [32q, 32q+32))
    {
        float a[NR] = {0.f, 0.f, 0.f, 0.f};
        const float4* wp = (const float4*)(W_lin + o * DD + q * 32);
        #pragma unroll
        for (int k = 0; k < 8; k++) {
            float4 w4 = wp[k];
            int d = q * 32 + 4 * k;
            #pragma unroll
            for (int r = 0; r < NR; r++) {
                float4 xv = *(const float4*)&xs[r][d];
                a[r] = fmaf(xv.x, w4.x, a[r]);
                a[r] = fmaf(xv.y, w4.y, a[r]);
                a[r] = fmaf(xv.z, w4.z, a[r]);
                a[r] = fmaf(xv.w, w4.w, a[r]);
            }
        }
        #pragma unroll
        for (int r = 0; r < NR; r++) pb2[q][r][o] = a[r];
    }
    __syncthreads();
    {
        float hreg = b_lin[o] + pb2[0][rr][o] + pb2[1][rr][o]
                              + pb2[2][rr][o] + pb2[3][rr][o];
        hs[rr][o] = hreg;
        h[(r0 + rr) * DD + o] = hreg;
    }
    __syncthreads();

    // dots: wave g handles row = g&3, side = g>>2 (0 = L, 1 = R)
    {
        int row = g & 3;
        const float* wa = W_att + (g >> 2) * DD;
        float p = hs[row][lane] * wa[lane] + hs[row][lane + 64] * wa[lane + 64];
        #pragma unroll
        for (int off = 32; off >= 1; off >>= 1) p += __shfl_down(p, off, 64);
        if (lane == 0) {
            if (g < 4) dotL[r0 + row] = p;
            else       dotR[r0 + row] = p;
        }
    }

    // GEMV2: hm1 = h @ W_m1[:, :128]^T + b_m1  (row stride 129), store BF16
    {
        float a[NR] = {0.f, 0.f, 0.f, 0.f};
        const float* w2 = W_m1 + o * (DD + 1) + q * 32;
        #pragma unroll
        for (int k = 0; k < 8; k++) {
            int d = q * 32 + 4 * k;
            float w0 = w2[4*k], w1 = w2[4*k+1], w2v = w2[4*k+2], w3 = w2[4*k+3];
            #pragma unroll
            for (int r = 0; r < NR; r++) {
                float4 xv = *(const float4*)&hs[r][d];
                a[r] = fmaf(xv.x, w0,  a[r]);
                a[r] = fmaf(xv.y, w1,  a[r]);
                a[r] = fmaf(xv.z, w2v, a[r]);
                a[r] = fmaf(xv.w, w3,  a[r]);
            }
        }
        #pragma unroll
        for (int r = 0; r < NR; r++) pb2[q][r][o] = a[r];
    }
    __syncthreads();
    {
        float v = b_m1[o] + pb2[0][rr][o] + pb2[1][rr][o]
                          + pb2[2][rr][o] + pb2[3][rr][o];
        hm1b[(r0 + rr) * DD + o] = __float2bfloat16(v);
    }

    // transpose duty: blocks 0..47, one 8-row slice each (global-only, no sync)
    if (blockIdx.x < 48 && t < 128) {
        const int w = blockIdx.x >> 4;
        const int s = blockIdx.x & 15;
        const float* src = (w == 0) ? W_m2 : (w == 1) ? W_o1 : W_o2;
        __hip_bfloat16* dst = (w == 0) ? Wt_m2 : (w == 1) ? Wt_o1 : Wt_o2;
        #pragma unroll
        for (int j = 0; j < 8; j++)
            dst[t * DD + s * 8 + j] = __float2bfloat16(src[(s * 8 + j) * DD + t]);
    }
}

// ---------------------------------------------------------------------------
// Kernel 2: fused attention + message aggregation + output network + LN.
// R7-proven structure; ONLY change: GEMV weights are bf16 (uint2 in-loop
// loads + shift-unpack) -> phase-C L2 traffic halved. No register prefetch,
// no packed-math experiments (both regressed ~13 us in R6/R8).
// ---------------------------------------------------------------------------
__global__ __launch_bounds__(512) void k_msgout(
    const float* __restrict__ adj, const unsigned int* __restrict__ hm1u,
    const float* __restrict__ dotL, const float* __restrict__ dotR,
    const float* __restrict__ W_m1, const float* __restrict__ W_att, const float* __restrict__ b_att,
    const __hip_bfloat16* __restrict__ Wt_m2, const float* __restrict__ b_m2,
    const __hip_bfloat16* __restrict__ Wt_o1, const float* __restrict__ b_o1,
    const __hip_bfloat16* __restrict__ Wt_o2, const float* __restrict__ b_o2,
    const float* __restrict__ h, const float* __restrict__ ln_g, const float* __restrict__ ln_b,
    float* __restrict__ out, float* __restrict__ out_adj)
{
    const int r0   = blockIdx.x * NR;
    const int b    = r0 >> 9;
    const int t    = threadIdx.x;        // 0..511
    const int g    = t >> 6;             // wave 0..7
    const int lane = t & 63;
    const int rr   = t >> 7;             // row-in-block (combine/LN phases)
    const int o    = t & 127;            // output dim   (combine/LN phases)
    const int oq   = t & 31;             // GEMV: output quad (o = 4*oq..+3)
    const int dg   = t >> 5;             // GEMV: d-group (d = dg*8..+7)

    __shared__ float2 aa[NR][NN];        // (adj, att) 16KB
    __shared__ float2 red[8][NR][64];    // sweep partials 16KB
    __shared__ float  pb[4][4][16][32];  // GEMV partials [j][r][dg][oq] 32KB
    __shared__ float  vs[NR][DD];        // GEMV ping
    __shared__ float  vs2[NR][DD];       // GEMV pong
    __shared__ float2 wa1s[64];
    __shared__ float  satt[NR];
    __shared__ float  redsc[2][2][NR];

    if (t < 64)
        wa1s[t] = make_float2(W_m1[(2 * t) * (DD + 1) + DD],
                              W_m1[(2 * t + 1) * (DD + 1) + DD]);
    const float wAdj = W_att[2 * DD];
    const float bA   = b_att[0];

    // ---- Phase A: attention + adj passthrough ----
    {
        float drm = dotR[b * NN + t];
        #pragma unroll
        for (int i = 0; i < NR; i++) {
            float a = adj[(r0 + i) * NN + t];
            out_adj[(r0 + i) * NN + t] = a;
            float z = dotL[r0 + i] + drm + a * wAdj + bA;
            aa[i][t] = make_float2(a, sigmoidf_(z));
        }
    }
    __syncthreads();

    if (g < NR) {   // s_att
        float s = 0.f;
        #pragma unroll
        for (int k = 0; k < 8; k++) s += aa[g][lane + 64 * k].y;
        #pragma unroll
        for (int off = 32; off >= 1; off >>= 1) s += __shfl_down(s, off, 64);
        if (lane == 0) satt[g] = s;
    }

    // ---- Phase B: neighbor sweep (hm1 as bf16 pairs: uint = 2 elems) ----
    {
        float2 agg[NR];
        #pragma unroll
        for (int r = 0; r < NR; r++) agg[r] = make_float2(0.f, 0.f);
        float2 wa = wa1s[lane];
        const unsigned int* hbase = hm1u + (size_t)b * NN * 64 + lane;
        #pragma unroll 4
        for (int m = g; m < NN; m += 8) {
            unsigned int u = hbase[m * 64];
            float2 hv;
            hv.x = __uint_as_float(u << 16);           // low bf16 -> f32 (exact)
            hv.y = __uint_as_float(u & 0xffff0000u);   // high bf16 -> f32
            #pragma unroll
            for (int r = 0; r < NR; r++) {
                float2 at = aa[r][m];                  // LDS broadcast
                float u0 = fmaxf(fmaf(at.x, wa.x, hv.x), 0.f);
                float u1 = fmaxf(fmaf(at.x, wa.y, hv.y), 0.f);
                agg[r].x = fmaf(at.y, u0, agg[r].x);
                agg[r].y = fmaf(at.y, u1, agg[r].y);
            }
        }
        #pragma unroll
        for (int r = 0; r < NR; r++) red[g][r][lane] = agg[r];
    }
    __syncthreads();
    {   // combine sweep partials -> vs = aggm
        float s = 0.f;
        #pragma unroll
        for (int gg = 0; gg < 8; gg++)
            s += ((const float*)&red[gg][rr][0])[o];
        vs[rr][o] = s;
    }
    __syncthreads();

    // ---- Phase C: three GEMVs with transposed bf16 weights (in-loop loads) ----
    const unsigned short* w1p = (const unsigned short*)Wt_m2;
    const unsigned short* w2p = (const unsigned short*)Wt_o1;
    const unsigned short* w3p = (const unsigned short*)Wt_o2;

    // GEMV1: v1 = aggm @ W_m2^T + b_m2 * s_att
    {
        float a0[4], a1[4], a2[4], a3[4];
        #pragma unroll
        for (int r = 0; r < 4; r++) { a0[r]=0.f; a1[r]=0.f; a2[r]=0.f; a3[r]=0.f; }
        #pragma unroll
        for (int k = 0; k < 8; k++) {
            int d = dg * 8 + k;
            float4 w4 = bf4(*(const uint2*)(w1p + d * DD + oq * 4));
            #pragma unroll
            for (int r = 0; r < 4; r++) {
                float xv = vs[r][d];
                a0[r] = fmaf(w4.x, xv, a0[r]);
                a1[r] = fmaf(w4.y, xv, a1[r]);
                a2[r] = fmaf(w4.z, xv, a2[r]);
                a3[r] = fmaf(w4.w, xv, a3[r]);
            }
        }
        #pragma unroll
        for (int r = 0; r < 4; r++) {
            pb[0][r][dg][oq] = a0[r]; pb[1][r][dg][oq] = a1[r];
            pb[2][r][dg][oq] = a2[r]; pb[3][r][dg][oq] = a3[r];
        }
    }
    __syncthreads();
    {
        float s = 0.f;
        #pragma unroll
        for (int d16 = 0; d16 < 16; d16++) s += pb[o & 3][rr][d16][o >> 2];
        vs2[rr][o] = s + b_m2[o] * satt[rr];
    }
    __syncthreads();

    // GEMV2: v2 = relu(v1 @ W_o1^T + b_o1)
    {
        float a0[4], a1[4], a2[4], a3[4];
        #pragma unroll
        for (int r = 0; r < 4; r++) { a0[r]=0.f; a1[r]=0.f; a2[r]=0.f; a3[r]=0.f; }
        #pragma unroll
        for (int k = 0; k < 8; k++) {
            int d = dg * 8 + k;
            float4 w4 = bf4(*(const uint2*)(w2p + d * DD + oq * 4));
            #pragma unroll
            for (int r = 0; r < 4; r++) {
                float xv = vs2[r][d];
                a0[r] = fmaf(w4.x, xv, a0[r]);
                a1[r] = fmaf(w4.y, xv, a1[r]);
                a2[r] = fmaf(w4.z, xv, a2[r]);
                a3[r] = fmaf(w4.w, xv, a3[r]);
            }
        }
        #pragma unroll
        for (int r = 0; r < 4; r++) {
            pb[0][r][dg][oq] = a0[r]; pb[1][r][dg][oq] = a1[r];
            pb[2][r][dg][oq] = a2[r]; pb[3][r][dg][oq] = a3[r];
        }
    }
    __syncthreads();
    {
        float s = 0.f;
        #pragma unroll
        for (int d16 = 0; d16 < 16; d16++) s += pb[o & 3][rr][d16][o >> 2];
        vs[rr][o] = fmaxf(s + b_o1[o], 0.f);
    }
    __syncthreads();

    // GEMV3: v3 = v2 @ W_o2^T + b_o2
    {
        float a0[4], a1[4], a2[4], a3[4];
        #pragma unroll
        for (int r = 0; r < 4; r++) { a0[r]=0.f; a1[r]=0.f; a2[r]=0.f; a3[r]=0.f; }
        #pragma unroll
        for (int k = 0; k < 8; k++) {
            int d = dg * 8 + k;
            float4 w4 = bf4(*(const uint2*)(w3p + d * DD + oq * 4));
            #pragma unroll
            for (int r = 0; r < 4; r++) {
                float xv = vs[r][d];
                a0[r] = fmaf(w4.x, xv, a0[r]);
                a1[r] = fmaf(w4.y, xv, a1[r]);
                a2[r] = fmaf(w4.z, xv, a2[r]);
                a3[r] = fmaf(w4.w, xv, a3[r]);
            }
        }
        #pragma unroll
        for (int r = 0; r < 4; r++) {
            pb[0][r][dg][oq] = a0[r]; pb[1][r][dg][oq] = a1[r];
            pb[2][r][dg][oq] = a2[r]; pb[3][r][dg][oq] = a3[r];
        }
    }
    __syncthreads();

    float v;
    {
        float s = 0.f;
        #pragma unroll
        for (int d16 = 0; d16 < 16; d16++) s += pb[o & 3][rr][d16][o >> 2];
        v = s + b_o2[o] + h[(r0 + rr) * DD + o];   // + residual
    }

    // layernorm over d (128 threads = 2 waves per row)
    {
        float p1 = v, p2 = v * v;
        #pragma unroll
        for (int off = 32; off >= 1; off >>= 1) {
            p1 += __shfl_down(p1, off, 64);
            p2 += __shfl_down(p2, off, 64);
        }
        int wid = (t >> 6) & 1;
        if ((t & 63) == 0) { redsc[wid][0][rr] = p1; redsc[wid][1][rr] = p2; }
    }
    __syncthreads();
    {
        float sum = redsc[0][0][rr] + redsc[1][0][rr];
        float sq  = redsc[0][1][rr] + redsc[1][1][rr];
        float mu  = sum * (1.0f / DD);
        float var = sq * (1.0f / DD) - mu * mu;
        float inv = rsqrtf(var + 1e-5f);
        out[(r0 + rr) * DD + o] = fmaxf(fmaf((v - mu) * inv, ln_g[o], ln_b[o]), 0.f);
    }
}

extern "C" void kernel_launch(void* const* d_in, const int* in_sizes, int n_in,
                              void* d_out, int out_size, void* d_ws, size_t ws_size,
                              hipStream_t stream)
{
    (void)in_sizes; (void)n_in; (void)out_size; (void)ws_size;
    const float* x     = (const float*)d_in[0];
    const float* adj   = (const float*)d_in[1];
    const float* W_lin = (const float*)d_in[2];
    const float* b_lin = (const float*)d_in[3];
    const float* W_m1  = (const float*)d_in[4];
    const float* b_m1  = (const float*)d_in[5];
    const float* W_m2  = (const float*)d_in[6];
    const float* b_m2  = (const float*)d_in[7];
    const float* W_att = (const float*)d_in[8];
    const float* b_att = (const float*)d_in[9];
    const float* W_o1  = (const float*)d_in[10];
    const float* b_o1  = (const float*)d_in[11];
    const float* W_o2  = (const float*)d_in[12];
    const float* b_o2  = (const float*)d_in[13];
    const float* ln_g  = (const float*)d_in[14];
    const float* ln_b  = (const float*)d_in[15];

    float* out     = (float*)d_out;
    float* out_adj = out + ROWS * DD;

    float* ws    = (float*)d_ws;
    float* hm1   = ws;                    // bf16, 131072 floats reserved
    float* dotL  = ws + 131072;           // 1024
    float* dotR  = ws + 132096;           // 1024
    float* h     = ws + 133120;           // 131072
    float* Wt_m2 = ws + 264192;           // bf16, 16384 floats reserved
    float* Wt_o1 = ws + 280576;           // bf16
    float* Wt_o2 = ws + 296960;           // bf16

    hipLaunchKernelGGL(k_rows, dim3(ROWS / NR), dim3(512), 0, stream,
                       x, W_lin, b_lin, W_m1, b_m1, W_att, W_m2, W_o1, W_o2,
                       h, (__hip_bfloat16*)hm1, dotL, dotR,
                       (__hip_bfloat16*)Wt_m2, (__hip_bfloat16*)Wt_o1, (__hip_bfloat16*)Wt_o2);
    hipLaunchKernelGGL(k_msgout, dim3(ROWS / NR), dim3(512), 0, stream,
                       adj, (const unsigned int*)hm1, dotL, dotR, W_m1, W_att, b_att,
                       (const __hip_bfloat16*)Wt_m2, b_m2,
                       (const __hip_bfloat16*)Wt_o1, b_o1,
                       (const __hip_bfloat16*)Wt_o2, b_o2,
                       h, ln_g, ln_b, out, out_adj);
}

// Round 10
// 25.275 us; speedup vs baseline: 1.5968x; 1.0303x over previous
//
#include <hip/hip_runtime.h>
#include <hip/hip_bf16.h>
#include <math.h>

#define NN 512
#define DD 128
#define ROWS 1024
#define NR 4

__device__ __forceinline__ float sigmoidf_(float z){ return 1.0f/(1.0f + __expf(-z)); }

// unpack 4 consecutive bf16 (as uint2) -> float4, exact
__device__ __forceinline__ float4 bf4(uint2 u) {
    float4 w;
    w.x = __uint_as_float(u.x << 16);
    w.y = __uint_as_float(u.x & 0xffff0000u);
    w.z = __uint_as_float(u.y << 16);
    w.w = __uint_as_float(u.y & 0xffff0000u);
    return w;
}

// ---------------------------------------------------------------------------
// Kernel 1 (512 threads, 256 blocks): per-row transforms, 4-way split-d GEMVs.
// (unchanged from R9 — proven)
// ---------------------------------------------------------------------------
__global__ __launch_bounds__(512) void k_rows(
    const float* __restrict__ x, const float* __restrict__ W_lin, const float* __restrict__ b_lin,
    const float* __restrict__ W_m1, const float* __restrict__ b_m1,
    const float* __restrict__ W_att,
    const float* __restrict__ W_m2, const float* __restrict__ W_o1, const float* __restrict__ W_o2,
    float* __restrict__ h, __hip_bfloat16* __restrict__ hm1b,
    float* __restrict__ dotL, float* __restrict__ dotR,
    __hip_bfloat16* __restrict__ Wt_m2, __hip_bfloat16* __restrict__ Wt_o1,
    __hip_bfloat16* __restrict__ Wt_o2)
{
    const int r0   = blockIdx.x * NR;
    const int t    = threadIdx.x;        // 0..511
    const int rr   = t >> 7;             // row-in-block (combine phases)
    const int o    = t & 127;            // output dim
    const int q    = t >> 7;             // d-quarter for split-d GEMVs
    const int g    = t >> 6;             // wave 0..7
    const int lane = t & 63;

    __shared__ float xs[NR][DD];         // x staging
    __shared__ float hs[NR][DD];         // h
    __shared__ float pb2[4][NR][DD];     // split-d partials

    // stage x: 512 floats = the block's 4 rows
    ((float*)xs)[t] = x[r0 * DD + t];
    __syncthreads();

    // GEMV1: h = x @ W_lin^T + b_lin  (thread (q,o) covers d in [32q, 32q+32))
    {
        float a[NR] = {0.f, 0.f, 0.f, 0.f};
        const float4* wp = (const float4*)(W_lin + o * DD + q * 32);
        #pragma unroll
        for (int k = 0; k < 8; k++) {
            float4 w4 = wp[k];
            int d = q * 32 + 4 * k;
            #pragma unroll
            for (int r = 0; r < NR; r++) {
                float4 xv = *(const float4*)&xs[r][d];
                a[r] = fmaf(xv.x, w4.x, a[r]);
                a[r] = fmaf(xv.y, w4.y, a[r]);
                a[r] = fmaf(xv.z, w4.z, a[r]);
                a[r] = fmaf(xv.w, w4.w, a[r]);
            }
        }
        #pragma unroll
        for (int r = 0; r < NR; r++) pb2[q][r][o] = a[r];
    }
    __syncthreads();
    {
        float hreg = b_lin[o] + pb2[0][rr][o] + pb2[1][rr][o]
                              + pb2[2][rr][o] + pb2[3][rr][o];
        hs[rr][o] = hreg;
        h[(r0 + rr) * DD + o] = hreg;
    }
    __syncthreads();

    // dots: wave g handles row = g&3, side = g>>2 (0 = L, 1 = R)
    {
        int row = g & 3;
        const float* wa = W_att + (g >> 2) * DD;
        float p = hs[row][lane] * wa[lane] + hs[row][lane + 64] * wa[lane + 64];
        #pragma unroll
        for (int off = 32; off >= 1; off >>= 1) p += __shfl_down(p, off, 64);
        if (lane == 0) {
            if (g < 4) dotL[r0 + row] = p;
            else       dotR[r0 + row] = p;
        }
    }

    // GEMV2: hm1 = h @ W_m1[:, :128]^T + b_m1  (row stride 129), store BF16
    {
        float a[NR] = {0.f, 0.f, 0.f, 0.f};
        const float* w2 = W_m1 + o * (DD + 1) + q * 32;
        #pragma unroll
        for (int k = 0; k < 8; k++) {
            int d = q * 32 + 4 * k;
            float w0 = w2[4*k], w1 = w2[4*k+1], w2v = w2[4*k+2], w3 = w2[4*k+3];
            #pragma unroll
            for (int r = 0; r < NR; r++) {
                float4 xv = *(const float4*)&hs[r][d];
                a[r] = fmaf(xv.x, w0,  a[r]);
                a[r] = fmaf(xv.y, w1,  a[r]);
                a[r] = fmaf(xv.z, w2v, a[r]);
                a[r] = fmaf(xv.w, w3,  a[r]);
            }
        }
        #pragma unroll
        for (int r = 0; r < NR; r++) pb2[q][r][o] = a[r];
    }
    __syncthreads();
    {
        float v = b_m1[o] + pb2[0][rr][o] + pb2[1][rr][o]
                          + pb2[2][rr][o] + pb2[3][rr][o];
        hm1b[(r0 + rr) * DD + o] = __float2bfloat16(v);
    }

    // transpose duty: blocks 0..47, one 8-row slice each (global-only, no sync)
    if (blockIdx.x < 48 && t < 128) {
        const int w = blockIdx.x >> 4;
        const int s = blockIdx.x & 15;
        const float* src = (w == 0) ? W_m2 : (w == 1) ? W_o1 : W_o2;
        __hip_bfloat16* dst = (w == 0) ? Wt_m2 : (w == 1) ? Wt_o1 : Wt_o2;
        #pragma unroll
        for (int j = 0; j < 8; j++)
            dst[t * DD + s * 8 + j] = __float2bfloat16(src[(s * 8 + j) * DD + t]);
    }
}

// ---------------------------------------------------------------------------
// Kernel 2 (1024 threads = 16 waves): fused attention + message agg + output.
// ONLY change vs R9: phase A split 2 rows per half, phase B m-sweep split 16
// ways (was 8) -> per-wave critical path halved, 4 waves/SIMD hide latency.
// Phases C/LN run on lower 512 threads (upper waves idle at barriers).
// ---------------------------------------------------------------------------
__global__ __launch_bounds__(1024) void k_msgout(
    const float* __restrict__ adj, const unsigned int* __restrict__ hm1u,
    const float* __restrict__ dotL, const float* __restrict__ dotR,
    const float* __restrict__ W_m1, const float* __restrict__ W_att, const float* __restrict__ b_att,
    const __hip_bfloat16* __restrict__ Wt_m2, const float* __restrict__ b_m2,
    const __hip_bfloat16* __restrict__ Wt_o1, const float* __restrict__ b_o1,
    const __hip_bfloat16* __restrict__ Wt_o2, const float* __restrict__ b_o2,
    const float* __restrict__ h, const float* __restrict__ ln_g, const float* __restrict__ ln_b,
    float* __restrict__ out, float* __restrict__ out_adj)
{
    const int r0   = blockIdx.x * NR;
    const int b    = r0 >> 9;
    const int t    = threadIdx.x;        // 0..1023
    const int g    = t >> 6;             // wave 0..15
    const int lane = t & 63;
    const int rr   = (t >> 7) & 3;       // row-in-block (combine/LN, t<512)
    const int o    = t & 127;            // output dim   (combine/LN, t<512)
    const int oq   = t & 31;             // GEMV: output quad
    const int dg   = (t >> 5) & 15;      // GEMV: d-group (t<512)

    __shared__ float2 aa[NR][NN];        // (adj, att) 16KB
    __shared__ float2 red[16][NR][64];   // sweep partials 32KB
    __shared__ float  pb[4][4][16][32];  // GEMV partials [j][r][dg][oq] 32KB
    __shared__ float  vs[NR][DD];        // GEMV ping
    __shared__ float  vs2[NR][DD];       // GEMV pong
    __shared__ float2 wa1s[64];
    __shared__ float  satt[NR];
    __shared__ float  redsc[2][2][NR];

    if (t < 64)
        wa1s[t] = make_float2(W_m1[(2 * t) * (DD + 1) + DD],
                              W_m1[(2 * t + 1) * (DD + 1) + DD]);
    const float wAdj = W_att[2 * DD];
    const float bA   = b_att[0];

    // ---- Phase A: attention + adj passthrough (2 rows per 512-thread half) ----
    {
        int col = t & 511;
        int i0  = (t >> 9) * 2;          // 0 or 2
        float drm = dotR[b * NN + col];
        #pragma unroll
        for (int i = 0; i < 2; i++) {
            int ri = i0 + i;
            float a = adj[(r0 + ri) * NN + col];
            out_adj[(r0 + ri) * NN + col] = a;
            float z = dotL[r0 + ri] + drm + a * wAdj + bA;
            aa[ri][col] = make_float2(a, sigmoidf_(z));
        }
    }
    __syncthreads();

    if (g < NR) {   // s_att: waves 0..3 reduce rows 0..3
        float s = 0.f;
        #pragma unroll
        for (int k = 0; k < 8; k++) s += aa[g][lane + 64 * k].y;
        #pragma unroll
        for (int off = 32; off >= 1; off >>= 1) s += __shfl_down(s, off, 64);
        if (lane == 0) satt[g] = s;
    }

    // ---- Phase B: neighbor sweep, 16 wave-groups split m ----
    {
        float2 agg[NR];
        #pragma unroll
        for (int r = 0; r < NR; r++) agg[r] = make_float2(0.f, 0.f);
        float2 wa = wa1s[lane];
        const unsigned int* hbase = hm1u + (size_t)b * NN * 64 + lane;
        #pragma unroll 4
        for (int m = g; m < NN; m += 16) {
            unsigned int u = hbase[m * 64];
            float2 hv;
            hv.x = __uint_as_float(u << 16);           // low bf16 -> f32 (exact)
            hv.y = __uint_as_float(u & 0xffff0000u);   // high bf16 -> f32
            #pragma unroll
            for (int r = 0; r < NR; r++) {
                float2 at = aa[r][m];                  // LDS broadcast
                float u0 = fmaxf(fmaf(at.x, wa.x, hv.x), 0.f);
                float u1 = fmaxf(fmaf(at.x, wa.y, hv.y), 0.f);
                agg[r].x = fmaf(at.y, u0, agg[r].x);
                agg[r].y = fmaf(at.y, u1, agg[r].y);
            }
        }
        #pragma unroll
        for (int r = 0; r < NR; r++) red[g][r][lane] = agg[r];
    }
    __syncthreads();
    if (t < 512) {   // combine sweep partials -> vs = aggm
        float s = 0.f;
        #pragma unroll
        for (int gg = 0; gg < 16; gg++)
            s += ((const float*)&red[gg][rr][0])[o];
        vs[rr][o] = s;
    }
    __syncthreads();

    // ---- Phase C: three GEMVs, bf16 weights, lower 512 threads ----
    const unsigned short* w1p = (const unsigned short*)Wt_m2;
    const unsigned short* w2p = (const unsigned short*)Wt_o1;
    const unsigned short* w3p = (const unsigned short*)Wt_o2;

    // GEMV1: v1 = aggm @ W_m2^T + b_m2 * s_att
    if (t < 512) {
        float a0[4], a1[4], a2[4], a3[4];
        #pragma unroll
        for (int r = 0; r < 4; r++) { a0[r]=0.f; a1[r]=0.f; a2[r]=0.f; a3[r]=0.f; }
        #pragma unroll
        for (int k = 0; k < 8; k++) {
            int d = dg * 8 + k;
            float4 w4 = bf4(*(const uint2*)(w1p + d * DD + oq * 4));
            #pragma unroll
            for (int r = 0; r < 4; r++) {
                float xv = vs[r][d];
                a0[r] = fmaf(w4.x, xv, a0[r]);
                a1[r] = fmaf(w4.y, xv, a1[r]);
                a2[r] = fmaf(w4.z, xv, a2[r]);
                a3[r] = fmaf(w4.w, xv, a3[r]);
            }
        }
        #pragma unroll
        for (int r = 0; r < 4; r++) {
            pb[0][r][dg][oq] = a0[r]; pb[1][r][dg][oq] = a1[r];
            pb[2][r][dg][oq] = a2[r]; pb[3][r][dg][oq] = a3[r];
        }
    }
    __syncthreads();
    if (t < 512) {
        float s = 0.f;
        #pragma unroll
        for (int d16 = 0; d16 < 16; d16++) s += pb[o & 3][rr][d16][o >> 2];
        vs2[rr][o] = s + b_m2[o] * satt[rr];
    }
    __syncthreads();

    // GEMV2: v2 = relu(v1 @ W_o1^T + b_o1)
    if (t < 512) {
        float a0[4], a1[4], a2[4], a3[4];
        #pragma unroll
        for (int r = 0; r < 4; r++) { a0[r]=0.f; a1[r]=0.f; a2[r]=0.f; a3[r]=0.f; }
        #pragma unroll
        for (int k = 0; k < 8; k++) {
            int d = dg * 8 + k;
            float4 w4 = bf4(*(const uint2*)(w2p + d * DD + oq * 4));
            #pragma unroll
            for (int r = 0; r < 4; r++) {
                float xv = vs2[r][d];
                a0[r] = fmaf(w4.x, xv, a0[r]);
                a1[r] = fmaf(w4.y, xv, a1[r]);
                a2[r] = fmaf(w4.z, xv, a2[r]);
                a3[r] = fmaf(w4.w, xv, a3[r]);
            }
        }
        #pragma unroll
        for (int r = 0; r < 4; r++) {
            pb[0][r][dg][oq] = a0[r]; pb[1][r][dg][oq] = a1[r];
            pb[2][r][dg][oq] = a2[r]; pb[3][r][dg][oq] = a3[r];
        }
    }
    __syncthreads();
    if (t < 512) {
        float s = 0.f;
        #pragma unroll
        for (int d16 = 0; d16 < 16; d16++) s += pb[o & 3][rr][d16][o >> 2];
        vs[rr][o] = fmaxf(s + b_o1[o], 0.f);
    }
    __syncthreads();

    // GEMV3: v3 = v2 @ W_o2^T + b_o2
    if (t < 512) {
        float a0[4], a1[4], a2[4], a3[4];
        #pragma unroll
        for (int r = 0; r < 4; r++) { a0[r]=0.f; a1[r]=0.f; a2[r]=0.f; a3[r]=0.f; }
        #pragma unroll
        for (int k = 0; k < 8; k++) {
            int d = dg * 8 + k;
            float4 w4 = bf4(*(const uint2*)(w3p + d * DD + oq * 4));
            #pragma unroll
            for (int r = 0; r < 4; r++) {
                float xv = vs[r][d];
                a0[r] = fmaf(w4.x, xv, a0[r]);
                a1[r] = fmaf(w4.y, xv, a1[r]);
                a2[r] = fmaf(w4.z, xv, a2[r]);
                a3[r] = fmaf(w4.w, xv, a3[r]);
            }
        }
        #pragma unroll
        for (int r = 0; r < 4; r++) {
            pb[0][r][dg][oq] = a0[r]; pb[1][r][dg][oq] = a1[r];
            pb[2][r][dg][oq] = a2[r]; pb[3][r][dg][oq] = a3[r];
        }
    }
    __syncthreads();

    if (t < 512) {
        float v;
        {
            float s = 0.f;
            #pragma unroll
            for (int d16 = 0; d16 < 16; d16++) s += pb[o & 3][rr][d16][o >> 2];
            v = s + b_o2[o] + h[(r0 + rr) * DD + o];   // + residual
        }

        // layernorm over d (128 threads = 2 waves per row)
        {
            float p1 = v, p2 = v * v;
            #pragma unroll
            for (int off = 32; off >= 1; off >>= 1) {
                p1 += __shfl_down(p1, off, 64);
                p2 += __shfl_down(p2, off, 64);
            }
            int wid = (t >> 6) & 1;
            if ((t & 63) == 0) { redsc[wid][0][rr] = p1; redsc[wid][1][rr] = p2; }
        }
        __syncthreads();
        {
            float sum = redsc[0][0][rr] + redsc[1][0][rr];
            float sq  = redsc[0][1][rr] + redsc[1][1][rr];
            float mu  = sum * (1.0f / DD);
            float var = sq * (1.0f / DD) - mu * mu;
            float inv = rsqrtf(var + 1e-5f);
            out[(r0 + rr) * DD + o] = fmaxf(fmaf((v - mu) * inv, ln_g[o], ln_b[o]), 0.f);
        }
    } else {
        __syncthreads();   // match barrier count for upper waves
    }
}

extern "C" void kernel_launch(void* const* d_in, const int* in_sizes, int n_in,
                              void* d_out, int out_size, void* d_ws, size_t ws_size,
                              hipStream_t stream)
{
    (void)in_sizes; (void)n_in; (void)out_size; (void)ws_size;
    const float* x     = (const float*)d_in[0];
    const float* adj   = (const float*)d_in[1];
    const float* W_lin = (const float*)d_in[2];
    const float* b_lin = (const float*)d_in[3];
    const float* W_m1  = (const float*)d_in[4];
    const float* b_m1  = (const float*)d_in[5];
    const float* W_m2  = (const float*)d_in[6];
    const float* b_m2  = (const float*)d_in[7];
    const float* W_att = (const float*)d_in[8];
    const float* b_att = (const float*)d_in[9];
    const float* W_o1  = (const float*)d_in[10];
    const float* b_o1  = (const float*)d_in[11];
    const float* W_o2  = (const float*)d_in[12];
    const float* b_o2  = (const float*)d_in[13];
    const float* ln_g  = (const float*)d_in[14];
    const float* ln_b  = (const float*)d_in[15];

    float* out     = (float*)d_out;
    float* out_adj = out + ROWS * DD;

    float* ws    = (float*)d_ws;
    float* hm1   = ws;                    // bf16, 131072 floats reserved
    float* dotL  = ws + 131072;           // 1024
    float* dotR  = ws + 132096;           // 1024
    float* h     = ws + 133120;           // 131072
    float* Wt_m2 = ws + 264192;           // bf16, 16384 floats reserved
    float* Wt_o1 = ws + 280576;           // bf16
    float* Wt_o2 = ws + 296960;           // bf16

    hipLaunchKernelGGL(k_rows, dim3(ROWS / NR), dim3(512), 0, stream,
                       x, W_lin, b_lin, W_m1, b_m1, W_att, W_m2, W_o1, W_o2,
                       h, (__hip_bfloat16*)hm1, dotL, dotR,
                       (__hip_bfloat16*)Wt_m2, (__hip_bfloat16*)Wt_o1, (__hip_bfloat16*)Wt_o2);
    hipLaunchKernelGGL(k_msgout, dim3(ROWS / NR), dim3(1024), 0, stream,
                       adj, (const unsigned int*)hm1, dotL, dotR, W_m1, W_att, b_att,
                       (const __hip_bfloat16*)Wt_m2, b_m2,
                       (const __hip_bfloat16*)Wt_o1, b_o1,
                       (const __hip_bfloat16*)Wt_o2, b_o2,
                       h, ln_g, ln_b, out, out_adj);
}